// Round 1
// baseline (8538.617 us; speedup 1.0000x reference)
//
#include <hip/hip_runtime.h>

typedef short short8 __attribute__((ext_vector_type(8)));
typedef float f32x16 __attribute__((ext_vector_type(16)));

#define NN 65536
#define TT 24
#define HD 256
#define G4 1024
#define NPB 64
#define NKT0 17   // layer0 k-tiles: 1 (x, K=16) + 16 (h, K=256)
#define NKT1 32   // layer1 k-tiles: 512/16
#define NCT 32    // 1024 gate-cols / 32

static __device__ __forceinline__ unsigned short f2bf(float f) {
  unsigned int u = __float_as_uint(f);
  unsigned int r = (u + 0x7fffu + ((u >> 16) & 1u)) >> 16;
  return (unsigned short)r;
}
static __device__ __forceinline__ float sigf(float x) {
  float e = __builtin_amdgcn_exp2f(-1.4426950408889634f * x);
  return __builtin_amdgcn_rcpf(1.0f + e);
}
static __device__ __forceinline__ float tanhf_(float x) {
  float e = __builtin_amdgcn_exp2f(-2.8853900817779268f * x);
  return 2.0f * __builtin_amdgcn_rcpf(1.0f + e) - 1.0f;
}

// W_eff[r][f] = sum_h W_ih0[r][h] * W_in[h][f]   (fold input projection into layer0)
__global__ void k_weff(const float* __restrict__ W_in, const float* __restrict__ W_ih,
                       float* __restrict__ weff) {
  int i = blockIdx.x * blockDim.x + threadIdx.x;  // 16384
  int r = i >> 4, f = i & 15;
  const float* wr = W_ih + (size_t)r * HD;
  float acc = 0.f;
  for (int h = 0; h < HD; ++h) acc += wr[h] * W_in[h * 16 + f];
  weff[i] = acc;
}

// Pack B operands (transposed weights) into per-lane MFMA fragment order, bf16.
// frag (kt, ct): elem (lane, e) = B[k = kt*16 + (lane>>5)*8 + e][col = ct*32 + (lane&31)]
// layer0: k<16 -> W_eff[col][k], else W_hh0[col][k-16]
// layer1: k<256 -> W_ih1[col][k], else W_hh1[col][k-256]
__global__ void k_pack(const float* __restrict__ weff, const float* __restrict__ W_ih,
                       const float* __restrict__ W_hh,
                       unsigned short* __restrict__ p0, unsigned short* __restrict__ p1) {
  int i = blockIdx.x * blockDim.x + threadIdx.x;
  const int NP0 = NKT0 * NCT * 512;
  if (i < NP0) {
    int e = i & 7, lane = (i >> 3) & 63, frag = i >> 9;
    int ct = frag % NCT, kt = frag / NCT;
    int k = kt * 16 + ((lane >> 5) << 3) + e;
    int col = ct * 32 + (lane & 31);
    float v = (kt == 0) ? weff[col * 16 + k] : W_hh[(size_t)col * HD + (k - 16)];
    p0[i] = f2bf(v);
  } else {
    int j = i - NP0;
    int e = j & 7, lane = (j >> 3) & 63, frag = j >> 9;
    int ct = frag % NCT, kt = frag / NCT;
    int k = kt * 16 + ((lane >> 5) << 3) + e;
    int col = ct * 32 + (lane & 31);
    float v = (k < HD) ? W_ih[(size_t)(G4 + col) * HD + k]
                       : W_hh[(size_t)(G4 + col) * HD + (k - HD)];
    p1[j] = f2bf(v);
  }
}

// Persistent LSTM kernel: block owns 64 nodes for all T steps.
// 8 waves: wave w owns j-window [w*32, w*32+32) of the per-gate hidden index.
// Wave tile per layer-step: 2 node-stripes (32 rows) x 4 gate-coltiles -> acc f32x16[2][4].
// c-state in VGPRs in MFMA C-layout; h-state bf16 in LDS (XOR-16B swizzle).
__global__ __launch_bounds__(512, 2) void k_main(
    const float* __restrict__ node_feat, const float* __restrict__ dyn_feat,
    const float* __restrict__ b_ih, const float* __restrict__ b_hh,
    const unsigned short* __restrict__ p0, const unsigned short* __restrict__ p1,
    float* __restrict__ out) {
  __shared__ __align__(16) unsigned short lh[2][NPB][HD];  // 64 KB
  const int tid = threadIdx.x;
  const int w = tid >> 6;
  const int lane = tid & 63;
  const int lr = lane & 31;   // A-row within stripe / B&C col within tile
  const int hi = lane >> 5;
  const int colj = w * 32 + lr;            // j in [0,256)
  const int swz = (lr & 15) << 3;          // row-XOR swizzle (8-elem = 16B granularity)

  // zero initial h state
  short8* lz = (short8*)&lh[0][0][0];
  short8 z8 = {0, 0, 0, 0, 0, 0, 0, 0};
#pragma unroll
  for (int i = 0; i < 8; ++i) lz[tid + i * 512] = z8;

  float bb0[4], bb1[4];
#pragma unroll
  for (int g = 0; g < 4; ++g) {
    bb0[g] = b_ih[g * HD + colj] + b_hh[g * HD + colj];
    bb1[g] = b_ih[G4 + g * HD + colj] + b_hh[G4 + g * HD + colj];
  }

  float c0[2][16], c1[2][16];
#pragma unroll
  for (int s = 0; s < 2; ++s)
#pragma unroll
    for (int r = 0; r < 16; ++r) { c0[s][r] = 0.f; c1[s][r] = 0.f; }

  const int gn0 = blockIdx.x * NPB + lr;  // global node of stripe-0 A-row
  const size_t OSL = (size_t)NN * HD;

  __syncthreads();

  for (int t = 0; t < TT; ++t) {
    // ========================= layer 0 =========================
    f32x16 acc[2][4];
#pragma unroll
    for (int s = 0; s < 2; ++s)
#pragma unroll
      for (int g = 0; g < 4; ++g)
#pragma unroll
        for (int r = 0; r < 16; ++r) acc[s][g][r] = bb0[g];

    {  // kt = 0: x fragment (16 features, exactly one K=16 tile)
      short8 ax[2];
#pragma unroll
      for (int s = 0; s < 2; ++s) {
        int gn = gn0 + s * 32;
#pragma unroll
        for (int e = 0; e < 8; ++e) {
          int f = hi * 8 + e;
          float v = (f < 5) ? node_feat[gn * 5 + f]
                            : dyn_feat[((size_t)gn * 11 + (f - 5)) * TT + t];
          ax[s][e] = (short)f2bf(v);
        }
      }
#pragma unroll
      for (int g = 0; g < 4; ++g) {
        short8 bf = *(const short8*)(p0 + ((size_t)(g * 8 + w) * 64 + lane) * 8);
        acc[0][g] = __builtin_amdgcn_mfma_f32_32x32x16_bf16(ax[0], bf, acc[0][g], 0, 0, 0);
        acc[1][g] = __builtin_amdgcn_mfma_f32_32x32x16_bf16(ax[1], bf, acc[1][g], 0, 0, 0);
      }
    }
#pragma unroll 4
    for (int kt = 1; kt < NKT0; ++kt) {
      int ksw = ((kt - 1) * 16 + hi * 8) ^ swz;
      short8 a0 = *(const short8*)&lh[0][lr][ksw];
      short8 a1 = *(const short8*)&lh[0][32 + lr][ksw];
#pragma unroll
      for (int g = 0; g < 4; ++g) {
        short8 bf = *(const short8*)(p0 + ((size_t)(kt * NCT + g * 8 + w) * 64 + lane) * 8);
        acc[0][g] = __builtin_amdgcn_mfma_f32_32x32x16_bf16(a0, bf, acc[0][g], 0, 0, 0);
        acc[1][g] = __builtin_amdgcn_mfma_f32_32x32x16_bf16(a1, bf, acc[1][g], 0, 0, 0);
      }
    }
    __syncthreads();  // all reads of h0(t-1) done before overwrite
    // epilogue layer 0: elementwise LSTM cell, write h0(t) to LDS
#pragma unroll
    for (int s = 0; s < 2; ++s) {
#pragma unroll
      for (int r = 0; r < 16; ++r) {
        int node = s * 32 + (r & 3) + ((r >> 2) << 3) + (hi << 2);
        float iv = acc[s][0][r], fv = acc[s][1][r], gv = acc[s][2][r], ov = acc[s][3][r];
        float c = sigf(fv) * c0[s][r] + sigf(iv) * tanhf_(gv);
        float h = sigf(ov) * tanhf_(c);
        c0[s][r] = c;
        lh[0][node][colj ^ ((node & 15) << 3)] = f2bf(h);
        if (t == TT - 1) {
          size_t gn = (size_t)blockIdx.x * NPB + node;
          out[0 * OSL + gn * HD + colj] = h;   // h, layer 0
          out[2 * OSL + gn * HD + colj] = c;   // c, layer 0
        }
      }
    }
    __syncthreads();
    // ========================= layer 1 =========================
#pragma unroll
    for (int s = 0; s < 2; ++s)
#pragma unroll
      for (int g = 0; g < 4; ++g)
#pragma unroll
        for (int r = 0; r < 16; ++r) acc[s][g][r] = bb1[g];

#pragma unroll 4
    for (int kt = 0; kt < NKT1; ++kt) {
      int which = kt >> 4;  // 0: h0(t) (input), 1: h1(t-1) (recurrent)
      int ksw = (((kt & 15) * 16) + hi * 8) ^ swz;
      short8 a0 = *(const short8*)&lh[which][lr][ksw];
      short8 a1 = *(const short8*)&lh[which][32 + lr][ksw];
#pragma unroll
      for (int g = 0; g < 4; ++g) {
        short8 bf = *(const short8*)(p1 + ((size_t)(kt * NCT + g * 8 + w) * 64 + lane) * 8);
        acc[0][g] = __builtin_amdgcn_mfma_f32_32x32x16_bf16(a0, bf, acc[0][g], 0, 0, 0);
        acc[1][g] = __builtin_amdgcn_mfma_f32_32x32x16_bf16(a1, bf, acc[1][g], 0, 0, 0);
      }
    }
    __syncthreads();
    // epilogue layer 1
#pragma unroll
    for (int s = 0; s < 2; ++s) {
#pragma unroll
      for (int r = 0; r < 16; ++r) {
        int node = s * 32 + (r & 3) + ((r >> 2) << 3) + (hi << 2);
        float iv = acc[s][0][r], fv = acc[s][1][r], gv = acc[s][2][r], ov = acc[s][3][r];
        float c = sigf(fv) * c1[s][r] + sigf(iv) * tanhf_(gv);
        float h = sigf(ov) * tanhf_(c);
        c1[s][r] = c;
        lh[1][node][colj ^ ((node & 15) << 3)] = f2bf(h);
        if (t == TT - 1) {
          size_t gn = (size_t)blockIdx.x * NPB + node;
          out[1 * OSL + gn * HD + colj] = h;   // h, layer 1
          out[3 * OSL + gn * HD + colj] = c;   // c, layer 1
        }
      }
    }
    __syncthreads();
  }
}

extern "C" void kernel_launch(void* const* d_in, const int* in_sizes, int n_in,
                              void* d_out, int out_size, void* d_ws, size_t ws_size,
                              hipStream_t stream) {
  const float* node_feat = (const float*)d_in[0];
  const float* dyn_feat  = (const float*)d_in[1];
  const float* W_in      = (const float*)d_in[2];
  const float* W_ih      = (const float*)d_in[3];
  const float* W_hh      = (const float*)d_in[4];
  const float* b_ih      = (const float*)d_in[5];
  const float* b_hh      = (const float*)d_in[6];
  float* out = (float*)d_out;

  // workspace layout: W_eff f32 (64 KB) | P0 bf16 (557056 B) | P1 bf16 (1 MB)
  float* weff = (float*)d_ws;
  unsigned short* p0 = (unsigned short*)((char*)d_ws + 65536);
  unsigned short* p1 = (unsigned short*)((char*)d_ws + 65536 + 557056);

  k_weff<<<64, 256, 0, stream>>>(W_in, W_ih, weff);
  k_pack<<<3136, 256, 0, stream>>>(weff, W_ih, W_hh, p0, p1);
  k_main<<<1024, 512, 0, stream>>>(node_feat, dyn_feat, b_ih, b_hh, p0, p1, out);
}

// Round 2
// 6625.423 us; speedup vs baseline: 1.2888x; 1.2888x over previous
//
#include <hip/hip_runtime.h>

typedef short short8 __attribute__((ext_vector_type(8)));
typedef float f32x16 __attribute__((ext_vector_type(16)));

#define NN 65536
#define TT 24
#define HD 256
#define G4 1024
#define NPB 64
#define NCT 32    // 1024 gate-cols / 32

static __device__ __forceinline__ unsigned short f2bf(float f) {
  unsigned int u = __float_as_uint(f);
  unsigned int r = (u + 0x7fffu + ((u >> 16) & 1u)) >> 16;
  return (unsigned short)r;
}
static __device__ __forceinline__ float sigf(float x) {
  float e = __builtin_amdgcn_exp2f(-1.4426950408889634f * x);
  return __builtin_amdgcn_rcpf(1.0f + e);
}
static __device__ __forceinline__ float tanhf_(float x) {
  float e = __builtin_amdgcn_exp2f(-2.8853900817779268f * x);
  return 2.0f * __builtin_amdgcn_rcpf(1.0f + e) - 1.0f;
}
static __device__ __forceinline__ short8 ldf(const unsigned short* p) {
  return *(const short8*)p;
}

// W_eff[r][f] = sum_h W_ih0[r][h] * W_in[h][f]   (fold input projection into layer0)
__global__ void k_weff(const float* __restrict__ W_in, const float* __restrict__ W_ih,
                       float* __restrict__ weff) {
  int i = blockIdx.x * blockDim.x + threadIdx.x;  // 16384
  int r = i >> 4, f = i & 15;
  const float* wr = W_ih + (size_t)r * HD;
  float acc = 0.f;
  for (int h = 0; h < HD; ++h) acc += wr[h] * W_in[h * 16 + f];
  weff[i] = acc;
}

// Pack B operands (transposed weights) into per-lane MFMA fragment order, bf16.
// frag (kt, ct): elem (lane, e) = B[k = kt*16 + (lane>>5)*8 + e][col = ct*32 + (lane&31)]
// layer0: k<16 -> W_eff[col][k], else W_hh0[col][k-16]
// layer1: k<256 -> W_ih1[col][k], else W_hh1[col][k-256]
__global__ void k_pack(const float* __restrict__ weff, const float* __restrict__ W_ih,
                       const float* __restrict__ W_hh,
                       unsigned short* __restrict__ p0, unsigned short* __restrict__ p1) {
  int i = blockIdx.x * blockDim.x + threadIdx.x;
  const int NP0 = 17 * NCT * 512;
  if (i < NP0) {
    int e = i & 7, lane = (i >> 3) & 63, frag = i >> 9;
    int ct = frag % NCT, kt = frag / NCT;
    int k = kt * 16 + ((lane >> 5) << 3) + e;
    int col = ct * 32 + (lane & 31);
    float v = (kt == 0) ? weff[col * 16 + k] : W_hh[(size_t)col * HD + (k - 16)];
    p0[i] = f2bf(v);
  } else {
    int j = i - NP0;
    int e = j & 7, lane = (j >> 3) & 63, frag = j >> 9;
    int ct = frag % NCT, kt = frag / NCT;
    int k = kt * 16 + ((lane >> 5) << 3) + e;
    int col = ct * 32 + (lane & 31);
    float v = (k < HD) ? W_ih[(size_t)(G4 + col) * HD + k]
                       : W_hh[(size_t)(G4 + col) * HD + (k - HD)];
    p1[j] = f2bf(v);
  }
}

// Persistent LSTM kernel: block owns 64 nodes for all T steps.
// 8 waves; wave w owns j-window [w*32, w*32+32).
// Each layer computed in TWO gate-pair passes to cap register pressure:
//   pass 0: gates (i=0, g=2) -> u = sig(i)*tanh(g)   (acc 64 regs, then u 32)
//   pass 1: gates (f=1, o=3) -> c = sig(f)*c + u; h = sig(o)*tanh(c)
// c-state in regs (MFMA C-layout); h-state bf16 in LDS (XOR-16B swizzle).
__global__ __launch_bounds__(512, 2) void k_main(
    const float* __restrict__ node_feat, const float* __restrict__ dyn_feat,
    const float* __restrict__ b_ih, const float* __restrict__ b_hh,
    const unsigned short* __restrict__ p0, const unsigned short* __restrict__ p1,
    float* __restrict__ out) {
  __shared__ __align__(16) unsigned short lh[2][NPB][HD];  // 64 KB
  const int tid = threadIdx.x;
  const int w = tid >> 6;
  const int lane = tid & 63;
  const int lr = lane & 31;   // A-row within stripe / B&C col within tile
  const int hi = lane >> 5;
  const int colj = w * 32 + lr;            // j in [0,256)
  const int swz = (lr & 15) << 3;          // row-XOR swizzle (16B granularity)

  // zero initial h state
  short8* lz = (short8*)&lh[0][0][0];
  short8 z8 = {0, 0, 0, 0, 0, 0, 0, 0};
#pragma unroll
  for (int i = 0; i < 8; ++i) lz[tid + i * 512] = z8;

  float bb0[4], bb1[4];
#pragma unroll
  for (int g = 0; g < 4; ++g) {
    bb0[g] = b_ih[g * HD + colj] + b_hh[g * HD + colj];
    bb1[g] = b_ih[G4 + g * HD + colj] + b_hh[G4 + g * HD + colj];
  }

  float c0[2][16], c1[2][16];
#pragma unroll
  for (int s = 0; s < 2; ++s)
#pragma unroll
    for (int r = 0; r < 16; ++r) { c0[s][r] = 0.f; c1[s][r] = 0.f; }

  const int gn0 = blockIdx.x * NPB + lr;  // global node of stripe-0 A-row
  const size_t OSL = (size_t)NN * HD;

  // per-lane B-fragment base: frag(kt,g) elems at pb + kt*16384 + g*4096
  const unsigned short* pb0 = p0 + w * 512 + lane * 8;
  const unsigned short* pb1 = p1 + w * 512 + lane * 8;

  __syncthreads();

  for (int t = 0; t < TT; ++t) {
    // x fragment for this t (16 features = one K=16 tile), built once, reused both passes
    short8 ax[2];
#pragma unroll
    for (int s = 0; s < 2; ++s) {
      int gn = gn0 + s * 32;
#pragma unroll
      for (int e = 0; e < 8; ++e) {
        int f = hi * 8 + e;
        float v = (f < 5) ? node_feat[gn * 5 + f]
                          : dyn_feat[((size_t)gn * 11 + (f - 5)) * TT + t];
        ax[s][e] = (short)f2bf(v);
      }
    }

    float u0[2][16];
    // ========================= layer 0 =========================
    {  // pass 0: gates i(0), g(2)
      f32x16 acc[2][2];
#pragma unroll
      for (int s = 0; s < 2; ++s)
#pragma unroll
        for (int r = 0; r < 16; ++r) { acc[s][0][r] = bb0[0]; acc[s][1][r] = bb0[2]; }
      {
        short8 b0 = ldf(pb0 + 0 * 4096), b1 = ldf(pb0 + 2 * 4096);
        acc[0][0] = __builtin_amdgcn_mfma_f32_32x32x16_bf16(ax[0], b0, acc[0][0], 0, 0, 0);
        acc[1][0] = __builtin_amdgcn_mfma_f32_32x32x16_bf16(ax[1], b0, acc[1][0], 0, 0, 0);
        acc[0][1] = __builtin_amdgcn_mfma_f32_32x32x16_bf16(ax[0], b1, acc[0][1], 0, 0, 0);
        acc[1][1] = __builtin_amdgcn_mfma_f32_32x32x16_bf16(ax[1], b1, acc[1][1], 0, 0, 0);
      }
#pragma unroll 2
      for (int kt = 1; kt < 17; ++kt) {
        int ksw = ((kt - 1) * 16 + hi * 8) ^ swz;
        short8 a0 = ldf(&lh[0][lr][ksw]);
        short8 a1 = ldf(&lh[0][32 + lr][ksw]);
        short8 b0 = ldf(pb0 + kt * 16384 + 0 * 4096);
        short8 b1 = ldf(pb0 + kt * 16384 + 2 * 4096);
        acc[0][0] = __builtin_amdgcn_mfma_f32_32x32x16_bf16(a0, b0, acc[0][0], 0, 0, 0);
        acc[1][0] = __builtin_amdgcn_mfma_f32_32x32x16_bf16(a1, b0, acc[1][0], 0, 0, 0);
        acc[0][1] = __builtin_amdgcn_mfma_f32_32x32x16_bf16(a0, b1, acc[0][1], 0, 0, 0);
        acc[1][1] = __builtin_amdgcn_mfma_f32_32x32x16_bf16(a1, b1, acc[1][1], 0, 0, 0);
      }
#pragma unroll
      for (int s = 0; s < 2; ++s)
#pragma unroll
        for (int r = 0; r < 16; ++r)
          u0[s][r] = sigf(acc[s][0][r]) * tanhf_(acc[s][1][r]);
    }
    f32x16 acc[2][2];  // pass 1: gates f(1), o(3)
#pragma unroll
    for (int s = 0; s < 2; ++s)
#pragma unroll
      for (int r = 0; r < 16; ++r) { acc[s][0][r] = bb0[1]; acc[s][1][r] = bb0[3]; }
    {
      short8 b0 = ldf(pb0 + 1 * 4096), b1 = ldf(pb0 + 3 * 4096);
      acc[0][0] = __builtin_amdgcn_mfma_f32_32x32x16_bf16(ax[0], b0, acc[0][0], 0, 0, 0);
      acc[1][0] = __builtin_amdgcn_mfma_f32_32x32x16_bf16(ax[1], b0, acc[1][0], 0, 0, 0);
      acc[0][1] = __builtin_amdgcn_mfma_f32_32x32x16_bf16(ax[0], b1, acc[0][1], 0, 0, 0);
      acc[1][1] = __builtin_amdgcn_mfma_f32_32x32x16_bf16(ax[1], b1, acc[1][1], 0, 0, 0);
    }
#pragma unroll 2
    for (int kt = 1; kt < 17; ++kt) {
      int ksw = ((kt - 1) * 16 + hi * 8) ^ swz;
      short8 a0 = ldf(&lh[0][lr][ksw]);
      short8 a1 = ldf(&lh[0][32 + lr][ksw]);
      short8 b0 = ldf(pb0 + kt * 16384 + 1 * 4096);
      short8 b1 = ldf(pb0 + kt * 16384 + 3 * 4096);
      acc[0][0] = __builtin_amdgcn_mfma_f32_32x32x16_bf16(a0, b0, acc[0][0], 0, 0, 0);
      acc[1][0] = __builtin_amdgcn_mfma_f32_32x32x16_bf16(a1, b0, acc[1][0], 0, 0, 0);
      acc[0][1] = __builtin_amdgcn_mfma_f32_32x32x16_bf16(a0, b1, acc[0][1], 0, 0, 0);
      acc[1][1] = __builtin_amdgcn_mfma_f32_32x32x16_bf16(a1, b1, acc[1][1], 0, 0, 0);
    }
    __syncthreads();  // all reads of h0(t-1) done before overwrite
#pragma unroll
    for (int s = 0; s < 2; ++s) {
#pragma unroll
      for (int r = 0; r < 16; ++r) {
        int node = s * 32 + (r & 3) + ((r >> 2) << 3) + (hi << 2);
        float c = sigf(acc[s][0][r]) * c0[s][r] + u0[s][r];
        float h = sigf(acc[s][1][r]) * tanhf_(c);
        c0[s][r] = c;
        lh[0][node][colj ^ ((node & 15) << 3)] = f2bf(h);
        if (t == TT - 1) {
          size_t gn = (size_t)blockIdx.x * NPB + node;
          out[0 * OSL + gn * HD + colj] = h;   // h, layer 0
          out[2 * OSL + gn * HD + colj] = c;   // c, layer 0
        }
      }
    }
    __syncthreads();
    // ========================= layer 1 =========================
    {  // pass 0: gates i(0), g(2)
      f32x16 acc1[2][2];
#pragma unroll
      for (int s = 0; s < 2; ++s)
#pragma unroll
        for (int r = 0; r < 16; ++r) { acc1[s][0][r] = bb1[0]; acc1[s][1][r] = bb1[2]; }
#pragma unroll 2
      for (int kt = 0; kt < 16; ++kt) {
        int ksw = (kt * 16 + hi * 8) ^ swz;
        short8 a0 = ldf(&lh[0][lr][ksw]);
        short8 a1 = ldf(&lh[0][32 + lr][ksw]);
        short8 b0 = ldf(pb1 + kt * 16384 + 0 * 4096);
        short8 b1 = ldf(pb1 + kt * 16384 + 2 * 4096);
        acc1[0][0] = __builtin_amdgcn_mfma_f32_32x32x16_bf16(a0, b0, acc1[0][0], 0, 0, 0);
        acc1[1][0] = __builtin_amdgcn_mfma_f32_32x32x16_bf16(a1, b0, acc1[1][0], 0, 0, 0);
        acc1[0][1] = __builtin_amdgcn_mfma_f32_32x32x16_bf16(a0, b1, acc1[0][1], 0, 0, 0);
        acc1[1][1] = __builtin_amdgcn_mfma_f32_32x32x16_bf16(a1, b1, acc1[1][1], 0, 0, 0);
      }
#pragma unroll 2
      for (int kt = 0; kt < 16; ++kt) {
        int ksw = (kt * 16 + hi * 8) ^ swz;
        short8 a0 = ldf(&lh[1][lr][ksw]);
        short8 a1 = ldf(&lh[1][32 + lr][ksw]);
        short8 b0 = ldf(pb1 + (kt + 16) * 16384 + 0 * 4096);
        short8 b1 = ldf(pb1 + (kt + 16) * 16384 + 2 * 4096);
        acc1[0][0] = __builtin_amdgcn_mfma_f32_32x32x16_bf16(a0, b0, acc1[0][0], 0, 0, 0);
        acc1[1][0] = __builtin_amdgcn_mfma_f32_32x32x16_bf16(a1, b0, acc1[1][0], 0, 0, 0);
        acc1[0][1] = __builtin_amdgcn_mfma_f32_32x32x16_bf16(a0, b1, acc1[0][1], 0, 0, 0);
        acc1[1][1] = __builtin_amdgcn_mfma_f32_32x32x16_bf16(a1, b1, acc1[1][1], 0, 0, 0);
      }
#pragma unroll
      for (int s = 0; s < 2; ++s)
#pragma unroll
        for (int r = 0; r < 16; ++r)
          u0[s][r] = sigf(acc1[s][0][r]) * tanhf_(acc1[s][1][r]);
    }
    f32x16 acc1[2][2];  // pass 1: gates f(1), o(3)
#pragma unroll
    for (int s = 0; s < 2; ++s)
#pragma unroll
      for (int r = 0; r < 16; ++r) { acc1[s][0][r] = bb1[1]; acc1[s][1][r] = bb1[3]; }
#pragma unroll 2
    for (int kt = 0; kt < 16; ++kt) {
      int ksw = (kt * 16 + hi * 8) ^ swz;
      short8 a0 = ldf(&lh[0][lr][ksw]);
      short8 a1 = ldf(&lh[0][32 + lr][ksw]);
      short8 b0 = ldf(pb1 + kt * 16384 + 1 * 4096);
      short8 b1 = ldf(pb1 + kt * 16384 + 3 * 4096);
      acc1[0][0] = __builtin_amdgcn_mfma_f32_32x32x16_bf16(a0, b0, acc1[0][0], 0, 0, 0);
      acc1[1][0] = __builtin_amdgcn_mfma_f32_32x32x16_bf16(a1, b0, acc1[1][0], 0, 0, 0);
      acc1[0][1] = __builtin_amdgcn_mfma_f32_32x32x16_bf16(a0, b1, acc1[0][1], 0, 0, 0);
      acc1[1][1] = __builtin_amdgcn_mfma_f32_32x32x16_bf16(a1, b1, acc1[1][1], 0, 0, 0);
    }
#pragma unroll 2
    for (int kt = 0; kt < 16; ++kt) {
      int ksw = (kt * 16 + hi * 8) ^ swz;
      short8 a0 = ldf(&lh[1][lr][ksw]);
      short8 a1 = ldf(&lh[1][32 + lr][ksw]);
      short8 b0 = ldf(pb1 + (kt + 16) * 16384 + 1 * 4096);
      short8 b1 = ldf(pb1 + (kt + 16) * 16384 + 3 * 4096);
      acc1[0][0] = __builtin_amdgcn_mfma_f32_32x32x16_bf16(a0, b0, acc1[0][0], 0, 0, 0);
      acc1[1][0] = __builtin_amdgcn_mfma_f32_32x32x16_bf16(a1, b0, acc1[1][0], 0, 0, 0);
      acc1[0][1] = __builtin_amdgcn_mfma_f32_32x32x16_bf16(a0, b1, acc1[0][1], 0, 0, 0);
      acc1[1][1] = __builtin_amdgcn_mfma_f32_32x32x16_bf16(a1, b1, acc1[1][1], 0, 0, 0);
    }
    __syncthreads();
#pragma unroll
    for (int s = 0; s < 2; ++s) {
#pragma unroll
      for (int r = 0; r < 16; ++r) {
        int node = s * 32 + (r & 3) + ((r >> 2) << 3) + (hi << 2);
        float c = sigf(acc1[s][0][r]) * c1[s][r] + u0[s][r];
        float h = sigf(acc1[s][1][r]) * tanhf_(c);
        c1[s][r] = c;
        lh[1][node][colj ^ ((node & 15) << 3)] = f2bf(h);
        if (t == TT - 1) {
          size_t gn = (size_t)blockIdx.x * NPB + node;
          out[1 * OSL + gn * HD + colj] = h;   // h, layer 1
          out[3 * OSL + gn * HD + colj] = c;   // c, layer 1
        }
      }
    }
    __syncthreads();
  }
}

extern "C" void kernel_launch(void* const* d_in, const int* in_sizes, int n_in,
                              void* d_out, int out_size, void* d_ws, size_t ws_size,
                              hipStream_t stream) {
  const float* node_feat = (const float*)d_in[0];
  const float* dyn_feat  = (const float*)d_in[1];
  const float* W_in      = (const float*)d_in[2];
  const float* W_ih      = (const float*)d_in[3];
  const float* W_hh      = (const float*)d_in[4];
  const float* b_ih      = (const float*)d_in[5];
  const float* b_hh      = (const float*)d_in[6];
  float* out = (float*)d_out;

  // workspace layout: W_eff f32 (64 KB) | P0 bf16 (557056 B) | P1 bf16 (1 MB)
  float* weff = (float*)d_ws;
  unsigned short* p0 = (unsigned short*)((char*)d_ws + 65536);
  unsigned short* p1 = (unsigned short*)((char*)d_ws + 65536 + 557056);

  k_weff<<<64, 256, 0, stream>>>(W_in, W_ih, weff);
  k_pack<<<3136, 256, 0, stream>>>(weff, W_ih, W_hh, p0, p1);
  k_main<<<1024, 512, 0, stream>>>(node_feat, dyn_feat, b_ih, b_hh, p0, p1, out);
}